// Round 2
// baseline (190.328 us; speedup 1.0000x reference)
//
#include <hip/hip_runtime.h>
#include <cstdint>
#include <cstddef>

#define B_ 16
#define C_ 512
#define N_ 1024
#define HEADS_ 8
#define D_ 64
#define CPG_ 16   // channels per group (512/32)

typedef __bf16 bf16;
typedef bf16 bf16x4 __attribute__((ext_vector_type(4)));
typedef bf16 bf16x8 __attribute__((ext_vector_type(8)));
typedef bf16 bf16x16 __attribute__((ext_vector_type(16)));
typedef float f32x4 __attribute__((ext_vector_type(4)));

__device__ __forceinline__ void gload16(void* lds, const void* g) {
    __builtin_amdgcn_global_load_lds(
        (__attribute__((address_space(1))) void*)(void*)g,
        (__attribute__((address_space(3))) void*)lds, 16, 0, 0);
}

// ---------------- fp32 -> bf16 weight conversion ----------------
__global__ __launch_bounds__(256) void f32_to_bf16_k(const float* __restrict__ s,
                                                     bf16* __restrict__ d, int n) {
    int i = (blockIdx.x * 256 + threadIdx.x) * 4;
    if (i < n) {
        f32x4 v = *(const f32x4*)(s + i);
        bf16x4 o = {(bf16)v[0], (bf16)v[1], (bf16)v[2], (bf16)v[3]};
        *(bf16x4*)(d + i) = o;
    }
}

// ---------------- GroupNorm -> xnT (b, n, c) bf16 ----------------
__global__ __launch_bounds__(256) void gn_kernel(const float* __restrict__ x,
                                                 const float* __restrict__ gamma,
                                                 const float* __restrict__ beta,
                                                 bf16* __restrict__ xnT) {
    const int blk = blockIdx.x;          // b*32 + g
    const int b = blk >> 5, g = blk & 31;
    const int c0 = g * CPG_;
    const float* xb = x + ((size_t)b * C_ + c0) * N_;
    const int t = threadIdx.x;

    f32x4 vals[CPG_];
    float sum = 0.f, ssq = 0.f;
#pragma unroll
    for (int c = 0; c < CPG_; ++c) {
        f32x4 v = *(const f32x4*)(xb + c * N_ + t * 4);
        vals[c] = v;
#pragma unroll
        for (int j = 0; j < 4; ++j) { sum += v[j]; ssq += v[j] * v[j]; }
    }
#pragma unroll
    for (int off = 32; off >= 1; off >>= 1) {
        sum += __shfl_xor(sum, off);
        ssq += __shfl_xor(ssq, off);
    }
    __shared__ float red[2][4];
    const int wv = t >> 6, lane = t & 63;
    if (lane == 0) { red[0][wv] = sum; red[1][wv] = ssq; }
    __syncthreads();
    sum = red[0][0] + red[0][1] + red[0][2] + red[0][3];
    ssq = red[1][0] + red[1][1] + red[1][2] + red[1][3];
    const float inv = 1.f / (float)(CPG_ * N_);
    float mean = sum * inv;
    float var = ssq * inv - mean * mean;
    float rstd = rsqrtf(var + 1e-5f);
    float ga[CPG_], be[CPG_];
#pragma unroll
    for (int c = 0; c < CPG_; ++c) {
        float gm = gamma[c0 + c] * rstd;
        ga[c] = gm;
        be[c] = beta[c0 + c] - mean * gm;
    }
#pragma unroll
    for (int j = 0; j < 4; ++j) {
        int n = t * 4 + j;
        bf16x16 o;
#pragma unroll
        for (int c = 0; c < CPG_; ++c) o[c] = (bf16)(vals[c][j] * ga[c] + be[c]);
        *(bf16x16*)(xnT + ((size_t)b * N_ + n) * C_ + c0) = o;
    }
}

// ---------------- generic gemm_bt, 128x128 tile, BK=64 ----------------
// C[b] = A (M,K) * Bt[b] (N,K)^T ; EPI 0 = qkv scatter, EPI 1 = proj+bias
template <int EPI>
__global__ __launch_bounds__(256) void gemm_bt(const bf16* __restrict__ A,
                                               const bf16* __restrict__ Bt,
                                               int M, int N, int K,
                                               void* __restrict__ o0,
                                               void* __restrict__ o1,
                                               void* __restrict__ o2,
                                               const float* __restrict__ bias) {
    __shared__ __align__(16) bf16 As[128][64];
    __shared__ __align__(16) bf16 Bs[128][64];
    const int t = threadIdx.x;
    const int lane = t & 63, wv = t >> 6;
    const int wr = wv >> 1, wc = wv & 1;
    const int bn = blockIdx.x, bm = blockIdx.y, b = blockIdx.z;
    const bf16* Ab = A + (size_t)bm * 128 * K;
    const bf16* Bb = Bt + ((size_t)b * N + (size_t)bn * 128) * K;

    f32x4 acc[4][4];
#pragma unroll
    for (int mi = 0; mi < 4; ++mi)
#pragma unroll
        for (int ni = 0; ni < 4; ++ni) acc[mi][ni] = f32x4{0.f, 0.f, 0.f, 0.f};

    const int nk = K >> 6;
    for (int kt = 0; kt < nk; ++kt) {
#pragma unroll
        for (int rnd = 0; rnd < 4; ++rnd) {
            int idx = rnd * 256 + t;
            int row = idx >> 3, pb = idx & 7;
            int srcb = pb ^ (row & 7);  // pre-swizzled source -> swizzled LDS
            gload16((char*)As + (size_t)idx * 16, Ab + (size_t)row * K + kt * 64 + srcb * 8);
        }
#pragma unroll
        for (int rnd = 0; rnd < 4; ++rnd) {
            int idx = rnd * 256 + t;
            int row = idx >> 3, pb = idx & 7;
            int srcb = pb ^ (row & 7);
            gload16((char*)Bs + (size_t)idx * 16, Bb + (size_t)row * K + kt * 64 + srcb * 8);
        }
        asm volatile("s_waitcnt vmcnt(0)" ::: "memory");
        __syncthreads();
#pragma unroll
        for (int ks = 0; ks < 2; ++ks) {
            bf16x8 af[4], bfr[4];
#pragma unroll
            for (int mi = 0; mi < 4; ++mi) {
                int r = wr * 64 + mi * 16 + (lane & 15);
                int bi = (ks * 4 + (lane >> 4)) ^ (r & 7);
                af[mi] = *(const bf16x8*)&As[r][bi * 8];
            }
#pragma unroll
            for (int ni = 0; ni < 4; ++ni) {
                int r = wc * 64 + ni * 16 + (lane & 15);
                int bi = (ks * 4 + (lane >> 4)) ^ (r & 7);
                bfr[ni] = *(const bf16x8*)&Bs[r][bi * 8];
            }
#pragma unroll
            for (int mi = 0; mi < 4; ++mi)
#pragma unroll
                for (int ni = 0; ni < 4; ++ni)
                    acc[mi][ni] = __builtin_amdgcn_mfma_f32_16x16x32_bf16(
                        af[mi], bfr[ni], acc[mi][ni], 0, 0, 0);
        }
        __syncthreads();
    }

    const int rowb = bm * 128 + wr * 64;
    const int colb = bn * 128 + wc * 64;
#pragma unroll
    for (int mi = 0; mi < 4; ++mi) {
#pragma unroll
        for (int ni = 0; ni < 4; ++ni) {
            int r0 = rowb + mi * 16 + (lane >> 4) * 4;
            int cc = colb + ni * 16 + (lane & 15);
            if constexpr (EPI == 0) {
                // qkv: rows [0,512)=q -> qT(b,h,n,d); [512,1024)=k fp32 (b,h,d,n); [1024,1536)=v bf16
                bf16* qT = (bf16*)o0;
                float* kf = (float*)o1;
                bf16* vb = (bf16*)o2;
                if (r0 < 512) {
                    int h = r0 >> 6, d = r0 & 63;
                    bf16x4 pk;
#pragma unroll
                    for (int j = 0; j < 4; ++j) pk[j] = (bf16)acc[mi][ni][j];
                    *(bf16x4*)(qT + (((size_t)b * HEADS_ + h) * N_ + cc) * D_ + d) = pk;
                } else if (r0 < 1024) {
                    int h = (r0 >> 6) - 8, d = r0 & 63;
                    float* kp = kf + (((size_t)b * HEADS_ + h) * D_ + d) * N_ + cc;
#pragma unroll
                    for (int j = 0; j < 4; ++j) kp[(size_t)j * N_] = acc[mi][ni][j];
                } else {
                    int h = (r0 >> 6) - 16, d = r0 & 63;
                    bf16* vp = vb + (((size_t)b * HEADS_ + h) * D_ + d) * N_ + cc;
#pragma unroll
                    for (int j = 0; j < 4; ++j) vp[(size_t)j * N_] = (bf16)acc[mi][ni][j];
                }
            } else {
                float* outp = (float*)o0;
#pragma unroll
                for (int j = 0; j < 4; ++j)
                    outp[((size_t)b * C_ + r0 + j) * N_ + cc] = acc[mi][ni][j] + bias[r0 + j];
            }
        }
    }
}

// ---------------- softmax over k rows (fp32 in, bf16 out) ----------------
__global__ __launch_bounds__(256) void softmax_k(const float* __restrict__ kf,
                                                 bf16* __restrict__ ksm) {
    const int row = blockIdx.x * 4 + (threadIdx.x >> 6);
    const int lane = threadIdx.x & 63;
    const float* rp = kf + (size_t)row * N_;
    f32x4 v[4];
    float mx = -1e30f;
#pragma unroll
    for (int i = 0; i < 4; ++i) {
        v[i] = *(const f32x4*)(rp + (lane + 64 * i) * 4);
#pragma unroll
        for (int j = 0; j < 4; ++j) mx = fmaxf(mx, v[i][j]);
    }
#pragma unroll
    for (int off = 32; off >= 1; off >>= 1) mx = fmaxf(mx, __shfl_xor(mx, off));
    float s = 0.f;
#pragma unroll
    for (int i = 0; i < 4; ++i)
#pragma unroll
        for (int j = 0; j < 4; ++j) { v[i][j] = __expf(v[i][j] - mx); s += v[i][j]; }
#pragma unroll
    for (int off = 32; off >= 1; off >>= 1) s += __shfl_xor(s, off);
    float inv = 1.f / s;
    bf16* op = ksm + (size_t)row * N_;
#pragma unroll
    for (int i = 0; i < 4; ++i) {
        bf16x4 o;
#pragma unroll
        for (int j = 0; j < 4; ++j) o[j] = (bf16)(v[i][j] * inv);
        *(bf16x4*)(op + (lane + 64 * i) * 4) = o;
    }
}

// ---------------- per-(b,h): att = ksm * v^T ; out2 = attT * qT^T ----------------
__global__ __launch_bounds__(256) void attn_kernel(const bf16* __restrict__ ksm,
                                                   const bf16* __restrict__ vb,
                                                   const bf16* __restrict__ qT,
                                                   bf16* __restrict__ o2T) {
    __shared__ float attp[2][64][64];            // 32 KB partial planes
    __shared__ __align__(16) bf16 attT[64][64];  // XOR-swizzled cols
    const int bh = blockIdx.x;
    const int b = bh >> 3, h = bh & 7;
    const int t = threadIdx.x, lane = t & 63, wv = t >> 6;
    const bf16* kb = ksm + (size_t)bh * D_ * N_;
    const bf16* vv = vb + (size_t)bh * D_ * N_;
    const bf16* qb = qT + (size_t)bh * N_ * D_;

    f32x4 acc[4][4];
#pragma unroll
    for (int mi = 0; mi < 4; ++mi)
#pragma unroll
        for (int ni = 0; ni < 4; ++ni) acc[mi][ni] = f32x4{0.f, 0.f, 0.f, 0.f};

    const int k0 = wv * 256;  // K split across 4 waves
    for (int kk = 0; kk < 256; kk += 32) {
        bf16x8 af[4], bfr[4];
#pragma unroll
        for (int mi = 0; mi < 4; ++mi)
            af[mi] = *(const bf16x8*)(kb + (size_t)(mi * 16 + (lane & 15)) * N_ + k0 + kk + (lane >> 4) * 8);
#pragma unroll
        for (int ni = 0; ni < 4; ++ni)
            bfr[ni] = *(const bf16x8*)(vv + (size_t)(ni * 16 + (lane & 15)) * N_ + k0 + kk + (lane >> 4) * 8);
#pragma unroll
        for (int mi = 0; mi < 4; ++mi)
#pragma unroll
            for (int ni = 0; ni < 4; ++ni)
                acc[mi][ni] = __builtin_amdgcn_mfma_f32_16x16x32_bf16(
                    af[mi], bfr[ni], acc[mi][ni], 0, 0, 0);
    }
    // cross-wave reduction: waves 0,1 write planes; waves 2,3 add; then fold 2 planes
    if (wv < 2) {
#pragma unroll
        for (int mi = 0; mi < 4; ++mi)
#pragma unroll
            for (int ni = 0; ni < 4; ++ni)
#pragma unroll
                for (int j = 0; j < 4; ++j)
                    attp[wv][mi * 16 + (lane >> 4) * 4 + j][ni * 16 + (lane & 15)] = acc[mi][ni][j];
    }
    __syncthreads();
    if (wv >= 2) {
#pragma unroll
        for (int mi = 0; mi < 4; ++mi)
#pragma unroll
            for (int ni = 0; ni < 4; ++ni)
#pragma unroll
                for (int j = 0; j < 4; ++j)
                    attp[wv - 2][mi * 16 + (lane >> 4) * 4 + j][ni * 16 + (lane & 15)] += acc[mi][ni][j];
    }
    __syncthreads();
    for (int i = t; i < 4096; i += 256) {
        int d = i >> 6, e = i & 63;
        float s = attp[0][d][e] + attp[1][d][e];
        attT[e][d ^ ((e & 7) << 3)] = (bf16)s;
    }
    __syncthreads();

    // phase 2: out2[e][n] = sum_d attT[e][d] * qT[n][d]
    for (int nc = 0; nc < 4; ++nc) {
        int n0 = wv * 256 + nc * 64;
        f32x4 a2[4][4];
#pragma unroll
        for (int mi = 0; mi < 4; ++mi)
#pragma unroll
            for (int ni = 0; ni < 4; ++ni) a2[mi][ni] = f32x4{0.f, 0.f, 0.f, 0.f};
#pragma unroll
        for (int ks = 0; ks < 2; ++ks) {
            bf16x8 af[4], bfr[4];
#pragma unroll
            for (int mi = 0; mi < 4; ++mi) {
                int r = mi * 16 + (lane & 15);
                int cb = ks * 32 + (lane >> 4) * 8;
                af[mi] = *(const bf16x8*)&attT[r][cb ^ ((r & 7) << 3)];
            }
#pragma unroll
            for (int ni = 0; ni < 4; ++ni)
                bfr[ni] = *(const bf16x8*)(qb + (size_t)(n0 + ni * 16 + (lane & 15)) * D_ + ks * 32 + (lane >> 4) * 8);
#pragma unroll
            for (int mi = 0; mi < 4; ++mi)
#pragma unroll
                for (int ni = 0; ni < 4; ++ni)
                    a2[mi][ni] = __builtin_amdgcn_mfma_f32_16x16x32_bf16(
                        af[mi], bfr[ni], a2[mi][ni], 0, 0, 0);
        }
#pragma unroll
        for (int mi = 0; mi < 4; ++mi) {
#pragma unroll
            for (int ni = 0; ni < 4; ++ni) {
                int e0 = mi * 16 + (lane >> 4) * 4;
                int nn = n0 + ni * 16 + (lane & 15);
                bf16x4 pk;
#pragma unroll
                for (int j = 0; j < 4; ++j) pk[j] = (bf16)a2[mi][ni][j];
                *(bf16x4*)(o2T + ((size_t)b * N_ + nn) * C_ + h * D_ + e0) = pk;
            }
        }
    }
}

extern "C" void kernel_launch(void* const* d_in, const int* in_sizes, int n_in,
                              void* d_out, int out_size, void* d_ws, size_t ws_size,
                              hipStream_t stream) {
    const float* x = (const float*)d_in[0];
    const float* gn_scale = (const float*)d_in[1];
    const float* gn_bias = (const float*)d_in[2];
    const float* qkv_w = (const float*)d_in[3];
    const float* proj_w = (const float*)d_in[4];
    const float* proj_b = (const float*)d_in[5];
    float* out = (float*)d_out;

    const size_t elems = (size_t)B_ * C_ * N_;  // 8,388,608
    char* w = (char*)d_ws;
    bf16* xnT = (bf16*)w;   w += elems * 2;                              // 16 MB (reused as o2T)
    bf16* qT = (bf16*)w;    w += (size_t)B_ * HEADS_ * N_ * D_ * 2;      // 16 MB
    float* kf = (float*)w;  w += (size_t)B_ * HEADS_ * D_ * N_ * 4;      // 32 MB
    bf16* ksm = (bf16*)w;   w += (size_t)B_ * HEADS_ * D_ * N_ * 2;      // 16 MB
    bf16* vbuf = (bf16*)w;  w += (size_t)B_ * HEADS_ * D_ * N_ * 2;      // 16 MB
    bf16* wqkv = (bf16*)w;  w += (size_t)3 * C_ * C_ * 2;                // 1.5 MB
    bf16* wproj = (bf16*)w; w += (size_t)C_ * C_ * 2;                    // 0.5 MB
    bf16* o2T = xnT;  // xnT is dead after the qkv GEMM; alias to save 16 MB

    f32_to_bf16_k<<<768, 256, 0, stream>>>(qkv_w, wqkv, 3 * C_ * C_);
    f32_to_bf16_k<<<256, 256, 0, stream>>>(proj_w, wproj, C_ * C_);
    gn_kernel<<<512, 256, 0, stream>>>(x, gn_scale, gn_bias, xnT);
    gemm_bt<0><<<dim3(8, 12, 16), 256, 0, stream>>>(wqkv, xnT, 1536, 1024, 512,
                                                    (void*)qT, (void*)kf, (void*)vbuf, nullptr);
    softmax_k<<<2048, 256, 0, stream>>>(kf, ksm);
    attn_kernel<<<128, 256, 0, stream>>>(ksm, vbuf, qT, o2T);
    gemm_bt<1><<<dim3(8, 4, 16), 256, 0, stream>>>(wproj, o2T, 512, 1024, 512,
                                                   (void*)out, nullptr, nullptr, proj_b);
}

// Round 3
// 188.033 us; speedup vs baseline: 1.0122x; 1.0122x over previous
//
#include <hip/hip_runtime.h>
#include <cstdint>
#include <cstddef>

#define B_ 16
#define C_ 512
#define N_ 1024
#define HEADS_ 8
#define D_ 64
#define CPG_ 16   // channels per group (512/32)

typedef __bf16 bf16;
typedef bf16 bf16x4 __attribute__((ext_vector_type(4)));
typedef bf16 bf16x8 __attribute__((ext_vector_type(8)));
typedef bf16 bf16x16 __attribute__((ext_vector_type(16)));
typedef float f32x4 __attribute__((ext_vector_type(4)));

__device__ __forceinline__ void gload16(void* lds, const void* g) {
    __builtin_amdgcn_global_load_lds(
        (__attribute__((address_space(1))) void*)(void*)g,
        (__attribute__((address_space(3))) void*)lds, 16, 0, 0);
}

// ---------------- fp32 -> bf16 weight conversion ----------------
__global__ __launch_bounds__(256) void f32_to_bf16_k(const float* __restrict__ s,
                                                     bf16* __restrict__ d, int n) {
    int i = (blockIdx.x * 256 + threadIdx.x) * 4;
    if (i < n) {
        f32x4 v = *(const f32x4*)(s + i);
        bf16x4 o = {(bf16)v[0], (bf16)v[1], (bf16)v[2], (bf16)v[3]};
        *(bf16x4*)(d + i) = o;
    }
}

// ---------------- GroupNorm -> xnT (b, n, c) bf16 ----------------
__global__ __launch_bounds__(256) void gn_kernel(const float* __restrict__ x,
                                                 const float* __restrict__ gamma,
                                                 const float* __restrict__ beta,
                                                 bf16* __restrict__ xnT) {
    const int blk = blockIdx.x;          // b*32 + g
    const int b = blk >> 5, g = blk & 31;
    const int c0 = g * CPG_;
    const float* xb = x + ((size_t)b * C_ + c0) * N_;
    const int t = threadIdx.x;

    f32x4 vals[CPG_];
    float sum = 0.f, ssq = 0.f;
#pragma unroll
    for (int c = 0; c < CPG_; ++c) {
        f32x4 v = *(const f32x4*)(xb + c * N_ + t * 4);
        vals[c] = v;
#pragma unroll
        for (int j = 0; j < 4; ++j) { sum += v[j]; ssq += v[j] * v[j]; }
    }
#pragma unroll
    for (int off = 32; off >= 1; off >>= 1) {
        sum += __shfl_xor(sum, off);
        ssq += __shfl_xor(ssq, off);
    }
    __shared__ float red[2][4];
    const int wv = t >> 6, lane = t & 63;
    if (lane == 0) { red[0][wv] = sum; red[1][wv] = ssq; }
    __syncthreads();
    sum = red[0][0] + red[0][1] + red[0][2] + red[0][3];
    ssq = red[1][0] + red[1][1] + red[1][2] + red[1][3];
    const float inv = 1.f / (float)(CPG_ * N_);
    float mean = sum * inv;
    float var = ssq * inv - mean * mean;
    float rstd = rsqrtf(var + 1e-5f);
    float ga[CPG_], be[CPG_];
#pragma unroll
    for (int c = 0; c < CPG_; ++c) {
        float gm = gamma[c0 + c] * rstd;
        ga[c] = gm;
        be[c] = beta[c0 + c] - mean * gm;
    }
#pragma unroll
    for (int j = 0; j < 4; ++j) {
        int n = t * 4 + j;
        bf16x16 o;
#pragma unroll
        for (int c = 0; c < CPG_; ++c) o[c] = (bf16)(vals[c][j] * ga[c] + be[c]);
        *(bf16x16*)(xnT + ((size_t)b * N_ + n) * C_ + c0) = o;
    }
}

// ---------------- gemm_bt, 128x128 tile, BK=64, double-buffered prefetch ----
// C[b] = A (M,K) * Bt[b] (N,K)^T ; EPI 0 = qkv scatter, EPI 1 = proj+bias
template <int EPI>
__global__ __launch_bounds__(256, 2) void gemm_bt(const bf16* __restrict__ A,
                                                  const bf16* __restrict__ Bt,
                                                  int M, int N, int K,
                                                  void* __restrict__ o0,
                                                  void* __restrict__ o1,
                                                  void* __restrict__ o2,
                                                  const float* __restrict__ bias) {
    __shared__ __align__(16) bf16 As[2][128][64];
    __shared__ __align__(16) bf16 Bs[2][128][64];
    const int t = threadIdx.x;
    const int lane = t & 63, wv = t >> 6;
    const int wr = wv >> 1, wc = wv & 1;
    const int bn = blockIdx.x, bm = blockIdx.y, b = blockIdx.z;
    const bf16* Ab = A + (size_t)bm * 128 * K;
    const bf16* Bb = Bt + ((size_t)b * N + (size_t)bn * 128) * K;

    f32x4 acc[4][4];
#pragma unroll
    for (int mi = 0; mi < 4; ++mi)
#pragma unroll
        for (int ni = 0; ni < 4; ++ni) acc[mi][ni] = f32x4{0.f, 0.f, 0.f, 0.f};

    const int nk = K >> 6;

    auto stage = [&](int buf, int kt) {
#pragma unroll
        for (int rnd = 0; rnd < 4; ++rnd) {
            int idx = rnd * 256 + t;
            int row = idx >> 3, pb = idx & 7;
            int srcb = pb ^ (row & 7);  // pre-swizzled source -> swizzled LDS
            gload16((char*)&As[buf][0][0] + (size_t)idx * 16,
                    Ab + (size_t)row * K + kt * 64 + srcb * 8);
        }
#pragma unroll
        for (int rnd = 0; rnd < 4; ++rnd) {
            int idx = rnd * 256 + t;
            int row = idx >> 3, pb = idx & 7;
            int srcb = pb ^ (row & 7);
            gload16((char*)&Bs[buf][0][0] + (size_t)idx * 16,
                    Bb + (size_t)row * K + kt * 64 + srcb * 8);
        }
    };
    auto compute = [&](int buf) {
#pragma unroll
        for (int ks = 0; ks < 2; ++ks) {
            bf16x8 af[4], bfr[4];
#pragma unroll
            for (int mi = 0; mi < 4; ++mi) {
                int r = wr * 64 + mi * 16 + (lane & 15);
                int bi = (ks * 4 + (lane >> 4)) ^ (r & 7);
                af[mi] = *(const bf16x8*)&As[buf][r][bi * 8];
            }
#pragma unroll
            for (int ni = 0; ni < 4; ++ni) {
                int r = wc * 64 + ni * 16 + (lane & 15);
                int bi = (ks * 4 + (lane >> 4)) ^ (r & 7);
                bfr[ni] = *(const bf16x8*)&Bs[buf][r][bi * 8];
            }
#pragma unroll
            for (int mi = 0; mi < 4; ++mi)
#pragma unroll
                for (int ni = 0; ni < 4; ++ni)
                    acc[mi][ni] = __builtin_amdgcn_mfma_f32_16x16x32_bf16(
                        af[mi], bfr[ni], acc[mi][ni], 0, 0, 0);
        }
    };

    // prologue: stage tile 0, drain, barrier
    stage(0, 0);
    asm volatile("s_waitcnt vmcnt(0)" ::: "memory");
    __syncthreads();
    // main loop: issue next-tile DMA, compute current under it, then drain+barrier
    for (int kt = 0; kt < nk - 1; ++kt) {
        const int cur = kt & 1;
        stage(cur ^ 1, kt + 1);
        compute(cur);
        asm volatile("s_waitcnt vmcnt(0)" ::: "memory");
        __syncthreads();
    }
    compute((nk - 1) & 1);

    const int rowb = bm * 128 + wr * 64;
    const int colb = bn * 128 + wc * 64;
#pragma unroll
    for (int mi = 0; mi < 4; ++mi) {
#pragma unroll
        for (int ni = 0; ni < 4; ++ni) {
            int r0 = rowb + mi * 16 + (lane >> 4) * 4;
            int cc = colb + ni * 16 + (lane & 15);
            if constexpr (EPI == 0) {
                // qkv: rows [0,512)=q -> qT(b,h,n,d); [512,1024)=k fp32 (b,h,d,n); [1024,1536)=v bf16
                bf16* qT = (bf16*)o0;
                float* kf = (float*)o1;
                bf16* vb = (bf16*)o2;
                if (r0 < 512) {
                    int h = r0 >> 6, d = r0 & 63;
                    bf16x4 pk;
#pragma unroll
                    for (int j = 0; j < 4; ++j) pk[j] = (bf16)acc[mi][ni][j];
                    *(bf16x4*)(qT + (((size_t)b * HEADS_ + h) * N_ + cc) * D_ + d) = pk;
                } else if (r0 < 1024) {
                    int h = (r0 >> 6) - 8, d = r0 & 63;
                    float* kp = kf + (((size_t)b * HEADS_ + h) * D_ + d) * N_ + cc;
#pragma unroll
                    for (int j = 0; j < 4; ++j) kp[(size_t)j * N_] = acc[mi][ni][j];
                } else {
                    int h = (r0 >> 6) - 16, d = r0 & 63;
                    bf16* vp = vb + (((size_t)b * HEADS_ + h) * D_ + d) * N_ + cc;
#pragma unroll
                    for (int j = 0; j < 4; ++j) vp[(size_t)j * N_] = (bf16)acc[mi][ni][j];
                }
            } else {
                float* outp = (float*)o0;
#pragma unroll
                for (int j = 0; j < 4; ++j)
                    outp[((size_t)b * C_ + r0 + j) * N_ + cc] = acc[mi][ni][j] + bias[r0 + j];
            }
        }
    }
}

// ---------------- softmax over k rows (fp32 in, bf16 out) ----------------
__global__ __launch_bounds__(256) void softmax_k(const float* __restrict__ kf,
                                                 bf16* __restrict__ ksm) {
    const int row = blockIdx.x * 4 + (threadIdx.x >> 6);
    const int lane = threadIdx.x & 63;
    const float* rp = kf + (size_t)row * N_;
    f32x4 v[4];
    float mx = -1e30f;
#pragma unroll
    for (int i = 0; i < 4; ++i) {
        v[i] = *(const f32x4*)(rp + (lane + 64 * i) * 4);
#pragma unroll
        for (int j = 0; j < 4; ++j) mx = fmaxf(mx, v[i][j]);
    }
#pragma unroll
    for (int off = 32; off >= 1; off >>= 1) mx = fmaxf(mx, __shfl_xor(mx, off));
    float s = 0.f;
#pragma unroll
    for (int i = 0; i < 4; ++i)
#pragma unroll
        for (int j = 0; j < 4; ++j) { v[i][j] = __expf(v[i][j] - mx); s += v[i][j]; }
#pragma unroll
    for (int off = 32; off >= 1; off >>= 1) s += __shfl_xor(s, off);
    float inv = 1.f / s;
    bf16* op = ksm + (size_t)row * N_;
#pragma unroll
    for (int i = 0; i < 4; ++i) {
        bf16x4 o;
#pragma unroll
        for (int j = 0; j < 4; ++j) o[j] = (bf16)(v[i][j] * inv);
        *(bf16x4*)(op + (lane + 64 * i) * 4) = o;
    }
}

// ---------------- per-(b,h): att = ksm * v^T ; out2 = attT * qT^T ----------------
__global__ __launch_bounds__(256) void attn_kernel(const bf16* __restrict__ ksm,
                                                   const bf16* __restrict__ vb,
                                                   const bf16* __restrict__ qT,
                                                   bf16* __restrict__ o2T) {
    __shared__ float attp[2][64][64];            // 32 KB partial planes
    __shared__ __align__(16) bf16 attT[64][64];  // XOR-swizzled cols
    const int bh = blockIdx.x;
    const int b = bh >> 3, h = bh & 7;
    const int t = threadIdx.x, lane = t & 63, wv = t >> 6;
    const bf16* kb = ksm + (size_t)bh * D_ * N_;
    const bf16* vv = vb + (size_t)bh * D_ * N_;
    const bf16* qb = qT + (size_t)bh * N_ * D_;

    f32x4 acc[4][4];
#pragma unroll
    for (int mi = 0; mi < 4; ++mi)
#pragma unroll
        for (int ni = 0; ni < 4; ++ni) acc[mi][ni] = f32x4{0.f, 0.f, 0.f, 0.f};

    const int k0 = wv * 256;  // K split across 4 waves
    for (int kk = 0; kk < 256; kk += 32) {
        bf16x8 af[4], bfr[4];
#pragma unroll
        for (int mi = 0; mi < 4; ++mi)
            af[mi] = *(const bf16x8*)(kb + (size_t)(mi * 16 + (lane & 15)) * N_ + k0 + kk + (lane >> 4) * 8);
#pragma unroll
        for (int ni = 0; ni < 4; ++ni)
            bfr[ni] = *(const bf16x8*)(vv + (size_t)(ni * 16 + (lane & 15)) * N_ + k0 + kk + (lane >> 4) * 8);
#pragma unroll
        for (int mi = 0; mi < 4; ++mi)
#pragma unroll
            for (int ni = 0; ni < 4; ++ni)
                acc[mi][ni] = __builtin_amdgcn_mfma_f32_16x16x32_bf16(
                    af[mi], bfr[ni], acc[mi][ni], 0, 0, 0);
    }
    // cross-wave reduction: waves 0,1 write planes; waves 2,3 add; then fold 2 planes
    if (wv < 2) {
#pragma unroll
        for (int mi = 0; mi < 4; ++mi)
#pragma unroll
            for (int ni = 0; ni < 4; ++ni)
#pragma unroll
                for (int j = 0; j < 4; ++j)
                    attp[wv][mi * 16 + (lane >> 4) * 4 + j][ni * 16 + (lane & 15)] = acc[mi][ni][j];
    }
    __syncthreads();
    if (wv >= 2) {
#pragma unroll
        for (int mi = 0; mi < 4; ++mi)
#pragma unroll
            for (int ni = 0; ni < 4; ++ni)
#pragma unroll
                for (int j = 0; j < 4; ++j)
                    attp[wv - 2][mi * 16 + (lane >> 4) * 4 + j][ni * 16 + (lane & 15)] += acc[mi][ni][j];
    }
    __syncthreads();
    for (int i = t; i < 4096; i += 256) {
        int d = i >> 6, e = i & 63;
        float s = attp[0][d][e] + attp[1][d][e];
        attT[e][d ^ ((e & 7) << 3)] = (bf16)s;
    }
    __syncthreads();

    // phase 2: out2[e][n] = sum_d attT[e][d] * qT[n][d]
    for (int nc = 0; nc < 4; ++nc) {
        int n0 = wv * 256 + nc * 64;
        f32x4 a2[4][4];
#pragma unroll
        for (int mi = 0; mi < 4; ++mi)
#pragma unroll
            for (int ni = 0; ni < 4; ++ni) a2[mi][ni] = f32x4{0.f, 0.f, 0.f, 0.f};
#pragma unroll
        for (int ks = 0; ks < 2; ++ks) {
            bf16x8 af[4], bfr[4];
#pragma unroll
            for (int mi = 0; mi < 4; ++mi) {
                int r = mi * 16 + (lane & 15);
                int cb = ks * 32 + (lane >> 4) * 8;
                af[mi] = *(const bf16x8*)&attT[r][cb ^ ((r & 7) << 3)];
            }
#pragma unroll
            for (int ni = 0; ni < 4; ++ni)
                bfr[ni] = *(const bf16x8*)(qb + (size_t)(n0 + ni * 16 + (lane & 15)) * D_ + ks * 32 + (lane >> 4) * 8);
#pragma unroll
            for (int mi = 0; mi < 4; ++mi)
#pragma unroll
                for (int ni = 0; ni < 4; ++ni)
                    a2[mi][ni] = __builtin_amdgcn_mfma_f32_16x16x32_bf16(
                        af[mi], bfr[ni], a2[mi][ni], 0, 0, 0);
        }
#pragma unroll
        for (int mi = 0; mi < 4; ++mi) {
#pragma unroll
            for (int ni = 0; ni < 4; ++ni) {
                int e0 = mi * 16 + (lane >> 4) * 4;
                int nn = n0 + ni * 16 + (lane & 15);
                bf16x4 pk;
#pragma unroll
                for (int j = 0; j < 4; ++j) pk[j] = (bf16)a2[mi][ni][j];
                *(bf16x4*)(o2T + ((size_t)b * N_ + nn) * C_ + h * D_ + e0) = pk;
            }
        }
    }
}

extern "C" void kernel_launch(void* const* d_in, const int* in_sizes, int n_in,
                              void* d_out, int out_size, void* d_ws, size_t ws_size,
                              hipStream_t stream) {
    const float* x = (const float*)d_in[0];
    const float* gn_scale = (const float*)d_in[1];
    const float* gn_bias = (const float*)d_in[2];
    const float* qkv_w = (const float*)d_in[3];
    const float* proj_w = (const float*)d_in[4];
    const float* proj_b = (const float*)d_in[5];
    float* out = (float*)d_out;

    const size_t elems = (size_t)B_ * C_ * N_;  // 8,388,608
    char* w = (char*)d_ws;
    bf16* xnT = (bf16*)w;   w += elems * 2;                              // 16 MB (reused as o2T)
    bf16* qT = (bf16*)w;    w += (size_t)B_ * HEADS_ * N_ * D_ * 2;      // 16 MB
    float* kf = (float*)w;  w += (size_t)B_ * HEADS_ * D_ * N_ * 4;      // 32 MB
    bf16* ksm = (bf16*)w;   w += (size_t)B_ * HEADS_ * D_ * N_ * 2;      // 16 MB
    bf16* vbuf = (bf16*)w;  w += (size_t)B_ * HEADS_ * D_ * N_ * 2;      // 16 MB
    bf16* wqkv = (bf16*)w;  w += (size_t)3 * C_ * C_ * 2;                // 1.5 MB
    bf16* wproj = (bf16*)w; w += (size_t)C_ * C_ * 2;                    // 0.5 MB
    bf16* o2T = xnT;  // xnT is dead after the qkv GEMM; alias to save 16 MB

    f32_to_bf16_k<<<768, 256, 0, stream>>>(qkv_w, wqkv, 3 * C_ * C_);
    f32_to_bf16_k<<<256, 256, 0, stream>>>(proj_w, wproj, C_ * C_);
    gn_kernel<<<512, 256, 0, stream>>>(x, gn_scale, gn_bias, xnT);
    gemm_bt<0><<<dim3(8, 12, 16), 256, 0, stream>>>(wqkv, xnT, 1536, 1024, 512,
                                                    (void*)qT, (void*)kf, (void*)vbuf, nullptr);
    softmax_k<<<2048, 256, 0, stream>>>(kf, ksm);
    attn_kernel<<<128, 256, 0, stream>>>(ksm, vbuf, qT, o2T);
    gemm_bt<1><<<dim3(8, 4, 16), 256, 0, stream>>>(wproj, o2T, 512, 1024, 512,
                                                   (void*)out, nullptr, nullptr, proj_b);
}

// Round 4
// 181.577 us; speedup vs baseline: 1.0482x; 1.0356x over previous
//
#include <hip/hip_runtime.h>
#include <cstdint>
#include <cstddef>

#define B_ 16
#define C_ 512
#define N_ 1024
#define HEADS_ 8
#define D_ 64
#define CPG_ 16   // channels per group (512/32)

typedef __bf16 bf16;
typedef bf16 bf16x4 __attribute__((ext_vector_type(4)));
typedef bf16 bf16x8 __attribute__((ext_vector_type(8)));
typedef bf16 bf16x16 __attribute__((ext_vector_type(16)));
typedef float f32x4 __attribute__((ext_vector_type(4)));

__device__ __forceinline__ void gload16(void* lds, const void* g) {
    __builtin_amdgcn_global_load_lds(
        (__attribute__((address_space(1))) void*)(void*)g,
        (__attribute__((address_space(3))) void*)lds, 16, 0, 0);
}

// ---------------- fp32 -> bf16 weight conversion ----------------
__global__ __launch_bounds__(256) void f32_to_bf16_k(const float* __restrict__ s,
                                                     bf16* __restrict__ d, int n) {
    int i = (blockIdx.x * 256 + threadIdx.x) * 4;
    if (i < n) {
        f32x4 v = *(const f32x4*)(s + i);
        bf16x4 o = {(bf16)v[0], (bf16)v[1], (bf16)v[2], (bf16)v[3]};
        *(bf16x4*)(d + i) = o;
    }
}

// ---------------- GroupNorm -> xnT (b, n, c) bf16 ----------------
__global__ __launch_bounds__(256) void gn_kernel(const float* __restrict__ x,
                                                 const float* __restrict__ gamma,
                                                 const float* __restrict__ beta,
                                                 bf16* __restrict__ xnT) {
    const int blk = blockIdx.x;          // b*32 + g
    const int b = blk >> 5, g = blk & 31;
    const int c0 = g * CPG_;
    const float* xb = x + ((size_t)b * C_ + c0) * N_;
    const int t = threadIdx.x;

    f32x4 vals[CPG_];
    float sum = 0.f, ssq = 0.f;
#pragma unroll
    for (int c = 0; c < CPG_; ++c) {
        f32x4 v = *(const f32x4*)(xb + c * N_ + t * 4);
        vals[c] = v;
#pragma unroll
        for (int j = 0; j < 4; ++j) { sum += v[j]; ssq += v[j] * v[j]; }
    }
#pragma unroll
    for (int off = 32; off >= 1; off >>= 1) {
        sum += __shfl_xor(sum, off);
        ssq += __shfl_xor(ssq, off);
    }
    __shared__ float red[2][4];
    const int wv = t >> 6, lane = t & 63;
    if (lane == 0) { red[0][wv] = sum; red[1][wv] = ssq; }
    __syncthreads();
    sum = red[0][0] + red[0][1] + red[0][2] + red[0][3];
    ssq = red[1][0] + red[1][1] + red[1][2] + red[1][3];
    const float inv = 1.f / (float)(CPG_ * N_);
    float mean = sum * inv;
    float var = ssq * inv - mean * mean;
    float rstd = rsqrtf(var + 1e-5f);
    float ga[CPG_], be[CPG_];
#pragma unroll
    for (int c = 0; c < CPG_; ++c) {
        float gm = gamma[c0 + c] * rstd;
        ga[c] = gm;
        be[c] = beta[c0 + c] - mean * gm;
    }
#pragma unroll
    for (int j = 0; j < 4; ++j) {
        int n = t * 4 + j;
        bf16x16 o;
#pragma unroll
        for (int c = 0; c < CPG_; ++c) o[c] = (bf16)(vals[c][j] * ga[c] + be[c]);
        *(bf16x16*)(xnT + ((size_t)b * N_ + n) * C_ + c0) = o;
    }
}

// ---- gemm_bt, 128x128 tile, BK=64, double-buffer + counted vmcnt(8) ----
// C[b] = A (M,K) * Bt[b] (N,K)^T ; EPI 0 = qkv scatter, EPI 1 = proj+bias
template <int EPI>
__global__ __launch_bounds__(256, 2) void gemm_bt(const bf16* __restrict__ A,
                                                  const bf16* __restrict__ Bt,
                                                  int M, int N, int K,
                                                  void* __restrict__ o0,
                                                  void* __restrict__ o1,
                                                  void* __restrict__ o2,
                                                  const float* __restrict__ bias) {
    __shared__ __align__(16) bf16 As[2][128][64];
    __shared__ __align__(16) bf16 Bs[2][128][64];
    const int t = threadIdx.x;
    const int lane = t & 63, wv = t >> 6;
    const int wr = wv >> 1, wc = wv & 1;
    const int bn = blockIdx.x, bm = blockIdx.y, b = blockIdx.z;
    const bf16* Ab = A + (size_t)bm * 128 * K;
    const bf16* Bb = Bt + ((size_t)b * N + (size_t)bn * 128) * K;

    f32x4 acc[4][4];
#pragma unroll
    for (int mi = 0; mi < 4; ++mi)
#pragma unroll
        for (int ni = 0; ni < 4; ++ni) acc[mi][ni] = f32x4{0.f, 0.f, 0.f, 0.f};

    const int nk = K >> 6;

    auto stage = [&](int buf, int kt) {
#pragma unroll
        for (int rnd = 0; rnd < 4; ++rnd) {
            int idx = rnd * 256 + t;
            int row = idx >> 3, pb = idx & 7;
            int srcb = pb ^ (row & 7);  // pre-swizzled source -> swizzled LDS
            gload16((char*)&As[buf][0][0] + (size_t)idx * 16,
                    Ab + (size_t)row * K + kt * 64 + srcb * 8);
        }
#pragma unroll
        for (int rnd = 0; rnd < 4; ++rnd) {
            int idx = rnd * 256 + t;
            int row = idx >> 3, pb = idx & 7;
            int srcb = pb ^ (row & 7);
            gload16((char*)&Bs[buf][0][0] + (size_t)idx * 16,
                    Bb + (size_t)row * K + kt * 64 + srcb * 8);
        }
    };
    auto compute = [&](int buf) {
#pragma unroll
        for (int ks = 0; ks < 2; ++ks) {
            bf16x8 af[4], bfr[4];
#pragma unroll
            for (int mi = 0; mi < 4; ++mi) {
                int r = wr * 64 + mi * 16 + (lane & 15);
                int bi = (ks * 4 + (lane >> 4)) ^ (r & 7);
                af[mi] = *(const bf16x8*)&As[buf][r][bi * 8];
            }
#pragma unroll
            for (int ni = 0; ni < 4; ++ni) {
                int r = wc * 64 + ni * 16 + (lane & 15);
                int bi = (ks * 4 + (lane >> 4)) ^ (r & 7);
                bfr[ni] = *(const bf16x8*)&Bs[buf][r][bi * 8];
            }
#pragma unroll
            for (int mi = 0; mi < 4; ++mi)
#pragma unroll
                for (int ni = 0; ni < 4; ++ni)
                    acc[mi][ni] = __builtin_amdgcn_mfma_f32_16x16x32_bf16(
                        af[mi], bfr[ni], acc[mi][ni], 0, 0, 0);
        }
    };

    // prologue: stage tile 0 only (stays in flight until first wait)
    stage(0, 0);
    // steady state: issue next-tile DMA, wait only for CURRENT tile (vmcnt(8)
    // = 8 newest loads may remain in flight), barrier, compute, barrier.
    for (int kt = 0; kt < nk; ++kt) {
        const int cur = kt & 1;
        if (kt + 1 < nk) {
            stage(cur ^ 1, kt + 1);
            asm volatile("s_waitcnt vmcnt(8)" ::: "memory");
        } else {
            asm volatile("s_waitcnt vmcnt(0)" ::: "memory");
        }
        __builtin_amdgcn_s_barrier();          // all waves' cur loads landed
        __builtin_amdgcn_sched_barrier(0);
        compute(cur);
        __builtin_amdgcn_s_barrier();          // all waves done reading cur
    }

    const int rowb = bm * 128 + wr * 64;
    const int colb = bn * 128 + wc * 64;
#pragma unroll
    for (int mi = 0; mi < 4; ++mi) {
#pragma unroll
        for (int ni = 0; ni < 4; ++ni) {
            int r0 = rowb + mi * 16 + (lane >> 4) * 4;
            int cc = colb + ni * 16 + (lane & 15);
            if constexpr (EPI == 0) {
                // qkv: [0,512)=q -> qT(b,h,n,d); [512,1024)=k logits bf16 (b,h,d,n);
                //      [1024,1536)=v bf16 (b,h,d,n)
                bf16* qT = (bf16*)o0;
                bf16* klog = (bf16*)o1;
                bf16* vb = (bf16*)o2;
                if (r0 < 512) {
                    int h = r0 >> 6, d = r0 & 63;
                    bf16x4 pk;
#pragma unroll
                    for (int j = 0; j < 4; ++j) pk[j] = (bf16)acc[mi][ni][j];
                    *(bf16x4*)(qT + (((size_t)b * HEADS_ + h) * N_ + cc) * D_ + d) = pk;
                } else {
                    bf16* dst = (r0 < 1024) ? klog : vb;
                    int h = (r0 >> 6) & 7, d = r0 & 63;
                    bf16* p = dst + (((size_t)b * HEADS_ + h) * D_ + d) * N_ + cc;
#pragma unroll
                    for (int j = 0; j < 4; ++j) p[(size_t)j * N_] = (bf16)acc[mi][ni][j];
                }
            } else {
                float* outp = (float*)o0;
#pragma unroll
                for (int j = 0; j < 4; ++j)
                    outp[((size_t)b * C_ + r0 + j) * N_ + cc] = acc[mi][ni][j] + bias[r0 + j];
            }
        }
    }
}

// ---------------- softmax over k rows (bf16 in, bf16 out) ----------------
__global__ __launch_bounds__(256) void softmax_k(const bf16* __restrict__ klog,
                                                 bf16* __restrict__ ksm) {
    const int row = blockIdx.x * 4 + (threadIdx.x >> 6);
    const int lane = threadIdx.x & 63;
    const bf16* rp = klog + (size_t)row * N_;
    float v[16];
    float mx = -1e30f;
#pragma unroll
    for (int i = 0; i < 2; ++i) {
        bf16x8 u = *(const bf16x8*)(rp + ((size_t)lane + 64 * i) * 8);
#pragma unroll
        for (int j = 0; j < 8; ++j) {
            v[i * 8 + j] = (float)u[j];
            mx = fmaxf(mx, v[i * 8 + j]);
        }
    }
#pragma unroll
    for (int off = 32; off >= 1; off >>= 1) mx = fmaxf(mx, __shfl_xor(mx, off));
    float s = 0.f;
#pragma unroll
    for (int i = 0; i < 16; ++i) { v[i] = __expf(v[i] - mx); s += v[i]; }
#pragma unroll
    for (int off = 32; off >= 1; off >>= 1) s += __shfl_xor(s, off);
    float inv = 1.f / s;
    bf16* op = ksm + (size_t)row * N_;
#pragma unroll
    for (int i = 0; i < 2; ++i) {
        bf16x8 o;
#pragma unroll
        for (int j = 0; j < 8; ++j) o[j] = (bf16)(v[i * 8 + j] * inv);
        *(bf16x8*)(op + ((size_t)lane + 64 * i) * 8) = o;
    }
}

// ------- attn1: partial att[d][e] per (b,h,K-half) -> fp32 (256 blocks) -------
__global__ __launch_bounds__(256) void attn1_kernel(const bf16* __restrict__ ksm,
                                                    const bf16* __restrict__ vb,
                                                    float* __restrict__ attP) {
    __shared__ float attp[2][64][64];
    const int blk = blockIdx.x;
    const int bh = blk >> 1, half = blk & 1;
    const int t = threadIdx.x, lane = t & 63, wv = t >> 6;
    const bf16* kb = ksm + (size_t)bh * D_ * N_;
    const bf16* vv = vb + (size_t)bh * D_ * N_;

    f32x4 acc[4][4];
#pragma unroll
    for (int mi = 0; mi < 4; ++mi)
#pragma unroll
        for (int ni = 0; ni < 4; ++ni) acc[mi][ni] = f32x4{0.f, 0.f, 0.f, 0.f};

    const int k0 = half * 512 + wv * 128;  // K split: 2 blocks x 4 waves x 128
#pragma unroll
    for (int kk = 0; kk < 128; kk += 32) {
        bf16x8 af[4], bfr[4];
#pragma unroll
        for (int mi = 0; mi < 4; ++mi)
            af[mi] = *(const bf16x8*)(kb + (size_t)(mi * 16 + (lane & 15)) * N_ + k0 + kk + (lane >> 4) * 8);
#pragma unroll
        for (int ni = 0; ni < 4; ++ni)
            bfr[ni] = *(const bf16x8*)(vv + (size_t)(ni * 16 + (lane & 15)) * N_ + k0 + kk + (lane >> 4) * 8);
#pragma unroll
        for (int mi = 0; mi < 4; ++mi)
#pragma unroll
            for (int ni = 0; ni < 4; ++ni)
                acc[mi][ni] = __builtin_amdgcn_mfma_f32_16x16x32_bf16(
                    af[mi], bfr[ni], acc[mi][ni], 0, 0, 0);
    }
    if (wv < 2) {
#pragma unroll
        for (int mi = 0; mi < 4; ++mi)
#pragma unroll
            for (int ni = 0; ni < 4; ++ni)
#pragma unroll
                for (int j = 0; j < 4; ++j)
                    attp[wv][mi * 16 + (lane >> 4) * 4 + j][ni * 16 + (lane & 15)] = acc[mi][ni][j];
    }
    __syncthreads();
    if (wv >= 2) {
#pragma unroll
        for (int mi = 0; mi < 4; ++mi)
#pragma unroll
            for (int ni = 0; ni < 4; ++ni)
#pragma unroll
                for (int j = 0; j < 4; ++j)
                    attp[wv - 2][mi * 16 + (lane >> 4) * 4 + j][ni * 16 + (lane & 15)] += acc[mi][ni][j];
    }
    __syncthreads();
    float* op = attP + (size_t)blk * 4096;  // [d][e], e contiguous
    for (int i = t; i < 4096; i += 256) {
        int d = i >> 6, e = i & 63;
        op[i] = attp[0][d][e] + attp[1][d][e];
    }
}

// ------- attn2: out2 = attT * qT^T, one n-quarter per block (512 blocks) ------
__global__ __launch_bounds__(256) void attn2_kernel(const float* __restrict__ attP,
                                                    const bf16* __restrict__ qT,
                                                    bf16* __restrict__ o2T) {
    __shared__ __align__(16) bf16 attT[64][64];  // XOR-swizzled cols
    const int blk = blockIdx.x;
    const int bh = blk >> 2, nc = blk & 3;
    const int b = bh >> 3, h = bh & 7;
    const int t = threadIdx.x, lane = t & 63, wv = t >> 6;
    const float* p0 = attP + (size_t)(bh * 2) * 4096;
    const float* p1 = p0 + 4096;
    for (int i = t; i < 4096; i += 256) {
        int d = i >> 6, e = i & 63;
        attT[e][d ^ ((e & 7) << 3)] = (bf16)(p0[i] + p1[i]);
    }
    __syncthreads();

    const bf16* qb = qT + (size_t)bh * N_ * D_;
    const int n0 = nc * 256 + wv * 64;
    f32x4 a2[4][4];
#pragma unroll
    for (int mi = 0; mi < 4; ++mi)
#pragma unroll
        for (int ni = 0; ni < 4; ++ni) a2[mi][ni] = f32x4{0.f, 0.f, 0.f, 0.f};
#pragma unroll
    for (int ks = 0; ks < 2; ++ks) {
        bf16x8 af[4], bfr[4];
#pragma unroll
        for (int mi = 0; mi < 4; ++mi) {
            int r = mi * 16 + (lane & 15);
            int cb = ks * 32 + (lane >> 4) * 8;
            af[mi] = *(const bf16x8*)&attT[r][cb ^ ((r & 7) << 3)];
        }
#pragma unroll
        for (int ni = 0; ni < 4; ++ni)
            bfr[ni] = *(const bf16x8*)(qb + (size_t)(n0 + ni * 16 + (lane & 15)) * D_ + ks * 32 + (lane >> 4) * 8);
#pragma unroll
        for (int mi = 0; mi < 4; ++mi)
#pragma unroll
            for (int ni = 0; ni < 4; ++ni)
                a2[mi][ni] = __builtin_amdgcn_mfma_f32_16x16x32_bf16(
                    af[mi], bfr[ni], a2[mi][ni], 0, 0, 0);
    }
#pragma unroll
    for (int mi = 0; mi < 4; ++mi) {
#pragma unroll
        for (int ni = 0; ni < 4; ++ni) {
            int e0 = mi * 16 + (lane >> 4) * 4;
            int nn = n0 + ni * 16 + (lane & 15);
            bf16x4 pk;
#pragma unroll
            for (int j = 0; j < 4; ++j) pk[j] = (bf16)a2[mi][ni][j];
            *(bf16x4*)(o2T + ((size_t)b * N_ + nn) * C_ + h * D_ + e0) = pk;
        }
    }
}

extern "C" void kernel_launch(void* const* d_in, const int* in_sizes, int n_in,
                              void* d_out, int out_size, void* d_ws, size_t ws_size,
                              hipStream_t stream) {
    const float* x = (const float*)d_in[0];
    const float* gn_scale = (const float*)d_in[1];
    const float* gn_bias = (const float*)d_in[2];
    const float* qkv_w = (const float*)d_in[3];
    const float* proj_w = (const float*)d_in[4];
    const float* proj_b = (const float*)d_in[5];
    float* out = (float*)d_out;

    const size_t elems = (size_t)B_ * C_ * N_;  // 8,388,608
    const size_t plane = (size_t)B_ * HEADS_ * D_ * N_;  // 8,388,608
    char* w = (char*)d_ws;
    bf16* xnT = (bf16*)w;   w += elems * 2;              // 16.8 MB (reused as o2T)
    bf16* qT = (bf16*)w;    w += plane * 2;              // 16.8 MB
    bf16* klog = (bf16*)w;  w += plane * 2;              // 16.8 MB
    bf16* ksm = (bf16*)w;   w += plane * 2;              // 16.8 MB
    bf16* vbuf = (bf16*)w;  w += plane * 2;              // 16.8 MB
    float* attP = (float*)w; w += (size_t)256 * 4096 * 4;  // 4.2 MB
    bf16* wqkv = (bf16*)w;  w += (size_t)3 * C_ * C_ * 2;  // 1.5 MB
    bf16* wproj = (bf16*)w; w += (size_t)C_ * C_ * 2;      // 0.5 MB
    bf16* o2T = xnT;  // xnT dead after qkv GEMM; alias

    f32_to_bf16_k<<<768, 256, 0, stream>>>(qkv_w, wqkv, 3 * C_ * C_);
    f32_to_bf16_k<<<256, 256, 0, stream>>>(proj_w, wproj, C_ * C_);
    gn_kernel<<<512, 256, 0, stream>>>(x, gn_scale, gn_bias, xnT);
    gemm_bt<0><<<dim3(8, 12, 16), 256, 0, stream>>>(wqkv, xnT, 1536, 1024, 512,
                                                    (void*)qT, (void*)klog, (void*)vbuf, nullptr);
    softmax_k<<<2048, 256, 0, stream>>>(klog, ksm);
    attn1_kernel<<<256, 256, 0, stream>>>(ksm, vbuf, attP);
    attn2_kernel<<<512, 256, 0, stream>>>(attP, qT, o2T);
    gemm_bt<1><<<dim3(8, 4, 16), 256, 0, stream>>>(wproj, o2T, 512, 1024, 512,
                                                   (void*)out, nullptr, nullptr, proj_b);
}

// Round 5
// 172.302 us; speedup vs baseline: 1.1046x; 1.0538x over previous
//
#include <hip/hip_runtime.h>
#include <cstdint>
#include <cstddef>

#define B_ 16
#define C_ 512
#define N_ 1024
#define HEADS_ 8
#define D_ 64
#define CPG_ 16   // channels per group (512/32)
#define KDIM 512  // GEMM K for both qkv and proj

typedef __bf16 bf16;
typedef bf16 bf16x4 __attribute__((ext_vector_type(4)));
typedef bf16 bf16x8 __attribute__((ext_vector_type(8)));
typedef bf16 bf16x16 __attribute__((ext_vector_type(16)));
typedef float f32x4 __attribute__((ext_vector_type(4)));

__device__ __forceinline__ void gload16(void* lds, const void* g) {
    __builtin_amdgcn_global_load_lds(
        (__attribute__((address_space(1))) void*)(void*)g,
        (__attribute__((address_space(3))) void*)lds, 16, 0, 0);
}

// ------------- fp32 -> bf16 weight conversion (both weights, one kernel) ----
__global__ __launch_bounds__(256) void convert_w(const float* __restrict__ qkv_w,
                                                 const float* __restrict__ proj_w,
                                                 bf16* __restrict__ wqkv,
                                                 bf16* __restrict__ wproj) {
    const int bid = blockIdx.x;
    const float* s;
    bf16* d;
    int i;
    if (bid < 768) { s = qkv_w; d = wqkv; i = bid * 1024 + threadIdx.x * 4; }
    else           { s = proj_w; d = wproj; i = (bid - 768) * 1024 + threadIdx.x * 4; }
    f32x4 v = *(const f32x4*)(s + i);
    bf16x4 o = {(bf16)v[0], (bf16)v[1], (bf16)v[2], (bf16)v[3]};
    *(bf16x4*)(d + i) = o;
}

// ---------------- GroupNorm -> xnT (b, n, c) bf16 ----------------
__global__ __launch_bounds__(256) void gn_kernel(const float* __restrict__ x,
                                                 const float* __restrict__ gamma,
                                                 const float* __restrict__ beta,
                                                 bf16* __restrict__ xnT) {
    const int blk = blockIdx.x;          // b*32 + g
    const int b = blk >> 5, g = blk & 31;
    const int c0 = g * CPG_;
    const float* xb = x + ((size_t)b * C_ + c0) * N_;
    const int t = threadIdx.x;

    f32x4 vals[CPG_];
    float sum = 0.f, ssq = 0.f;
#pragma unroll
    for (int c = 0; c < CPG_; ++c) {
        f32x4 v = *(const f32x4*)(xb + c * N_ + t * 4);
        vals[c] = v;
#pragma unroll
        for (int j = 0; j < 4; ++j) { sum += v[j]; ssq += v[j] * v[j]; }
    }
#pragma unroll
    for (int off = 32; off >= 1; off >>= 1) {
        sum += __shfl_xor(sum, off);
        ssq += __shfl_xor(ssq, off);
    }
    __shared__ float red[2][4];
    const int wv = t >> 6, lane = t & 63;
    if (lane == 0) { red[0][wv] = sum; red[1][wv] = ssq; }
    __syncthreads();
    sum = red[0][0] + red[0][1] + red[0][2] + red[0][3];
    ssq = red[1][0] + red[1][1] + red[1][2] + red[1][3];
    const float inv = 1.f / (float)(CPG_ * N_);
    float mean = sum * inv;
    float var = ssq * inv - mean * mean;
    float rstd = rsqrtf(var + 1e-5f);
    float ga[CPG_], be[CPG_];
#pragma unroll
    for (int c = 0; c < CPG_; ++c) {
        float gm = gamma[c0 + c] * rstd;
        ga[c] = gm;
        be[c] = beta[c0 + c] - mean * gm;
    }
#pragma unroll
    for (int j = 0; j < 4; ++j) {
        int n = t * 4 + j;
        bf16x16 o;
#pragma unroll
        for (int c = 0; c < CPG_; ++c) o[c] = (bf16)(vals[c][j] * ga[c] + be[c]);
        *(bf16x16*)(xnT + ((size_t)b * N_ + n) * C_ + c0) = o;
    }
}

// ---- qkv GEMM: 128x128 tile, BK=64, dbuf + counted vmcnt(8), K=512 ----
// qkv[b] = wqkv (1536,512) * xnT[b] (1024,512)^T, scatter epilogue
__global__ __launch_bounds__(256, 2) void qkv_gemm(const bf16* __restrict__ A,
                                                   const bf16* __restrict__ Bt,
                                                   bf16* __restrict__ qT,
                                                   bf16* __restrict__ klog,
                                                   bf16* __restrict__ vb) {
    __shared__ __align__(16) bf16 As[2][128][64];
    __shared__ __align__(16) bf16 Bs[2][128][64];
    const int t = threadIdx.x;
    const int lane = t & 63, wv = t >> 6;
    const int wr = wv >> 1, wc = wv & 1;
    const int bn = blockIdx.x, bm = blockIdx.y, b = blockIdx.z;
    const bf16* Ab = A + (size_t)bm * 128 * KDIM;
    const bf16* Bb = Bt + ((size_t)b * N_ + (size_t)bn * 128) * KDIM;

    f32x4 acc[4][4];
#pragma unroll
    for (int mi = 0; mi < 4; ++mi)
#pragma unroll
        for (int ni = 0; ni < 4; ++ni) acc[mi][ni] = f32x4{0.f, 0.f, 0.f, 0.f};

    const int nk = KDIM >> 6;  // 8

    auto stage = [&](int buf, int kt) {
#pragma unroll
        for (int rnd = 0; rnd < 4; ++rnd) {
            int idx = rnd * 256 + t;
            int row = idx >> 3, pb = idx & 7;
            int srcb = pb ^ (row & 7);  // pre-swizzled source -> swizzled LDS
            gload16((char*)&As[buf][0][0] + (size_t)idx * 16,
                    Ab + (size_t)row * KDIM + kt * 64 + srcb * 8);
        }
#pragma unroll
        for (int rnd = 0; rnd < 4; ++rnd) {
            int idx = rnd * 256 + t;
            int row = idx >> 3, pb = idx & 7;
            int srcb = pb ^ (row & 7);
            gload16((char*)&Bs[buf][0][0] + (size_t)idx * 16,
                    Bb + (size_t)row * KDIM + kt * 64 + srcb * 8);
        }
    };
    auto compute = [&](int buf) {
#pragma unroll
        for (int ks = 0; ks < 2; ++ks) {
            bf16x8 af[4], bfr[4];
#pragma unroll
            for (int mi = 0; mi < 4; ++mi) {
                int r = wr * 64 + mi * 16 + (lane & 15);
                int bi = (ks * 4 + (lane >> 4)) ^ (r & 7);
                af[mi] = *(const bf16x8*)&As[buf][r][bi * 8];
            }
#pragma unroll
            for (int ni = 0; ni < 4; ++ni) {
                int r = wc * 64 + ni * 16 + (lane & 15);
                int bi = (ks * 4 + (lane >> 4)) ^ (r & 7);
                bfr[ni] = *(const bf16x8*)&Bs[buf][r][bi * 8];
            }
#pragma unroll
            for (int mi = 0; mi < 4; ++mi)
#pragma unroll
                for (int ni = 0; ni < 4; ++ni)
                    acc[mi][ni] = __builtin_amdgcn_mfma_f32_16x16x32_bf16(
                        af[mi], bfr[ni], acc[mi][ni], 0, 0, 0);
        }
    };

    stage(0, 0);
    for (int kt = 0; kt < nk; ++kt) {
        const int cur = kt & 1;
        if (kt + 1 < nk) {
            stage(cur ^ 1, kt + 1);
            asm volatile("s_waitcnt vmcnt(8)" ::: "memory");
        } else {
            asm volatile("s_waitcnt vmcnt(0)" ::: "memory");
        }
        __builtin_amdgcn_s_barrier();
        __builtin_amdgcn_sched_barrier(0);
        compute(cur);
        __builtin_amdgcn_s_barrier();
    }

    const int rowb = bm * 128 + wr * 64;
    const int colb = bn * 128 + wc * 64;
#pragma unroll
    for (int mi = 0; mi < 4; ++mi) {
#pragma unroll
        for (int ni = 0; ni < 4; ++ni) {
            int r0 = rowb + mi * 16 + (lane >> 4) * 4;
            int cc = colb + ni * 16 + (lane & 15);
            // rows [0,512)=q -> qT(b,h,n,d); [512,1024)=k logits; [1024,1536)=v
            if (r0 < 512) {
                int h = r0 >> 6, d = r0 & 63;
                bf16x4 pk;
#pragma unroll
                for (int j = 0; j < 4; ++j) pk[j] = (bf16)acc[mi][ni][j];
                *(bf16x4*)(qT + (((size_t)b * HEADS_ + h) * N_ + cc) * D_ + d) = pk;
            } else {
                bf16* dst = (r0 < 1024) ? klog : vb;
                int h = (r0 >> 6) & 7, d = r0 & 63;
                bf16* p = dst + (((size_t)b * HEADS_ + h) * D_ + d) * N_ + cc;
#pragma unroll
                for (int j = 0; j < 4; ++j) p[(size_t)j * N_] = (bf16)acc[mi][ni][j];
            }
        }
    }
}

// ---- proj GEMM: identical loop, bias+fp32 epilogue ----
__global__ __launch_bounds__(256, 2) void proj_gemm(const bf16* __restrict__ A,
                                                    const bf16* __restrict__ Bt,
                                                    float* __restrict__ outp,
                                                    const float* __restrict__ bias) {
    __shared__ __align__(16) bf16 As[2][128][64];
    __shared__ __align__(16) bf16 Bs[2][128][64];
    const int t = threadIdx.x;
    const int lane = t & 63, wv = t >> 6;
    const int wr = wv >> 1, wc = wv & 1;
    const int bn = blockIdx.x, bm = blockIdx.y, b = blockIdx.z;
    const bf16* Ab = A + (size_t)bm * 128 * KDIM;
    const bf16* Bb = Bt + ((size_t)b * N_ + (size_t)bn * 128) * KDIM;

    f32x4 acc[4][4];
#pragma unroll
    for (int mi = 0; mi < 4; ++mi)
#pragma unroll
        for (int ni = 0; ni < 4; ++ni) acc[mi][ni] = f32x4{0.f, 0.f, 0.f, 0.f};

    const int nk = KDIM >> 6;

    auto stage = [&](int buf, int kt) {
#pragma unroll
        for (int rnd = 0; rnd < 4; ++rnd) {
            int idx = rnd * 256 + t;
            int row = idx >> 3, pb = idx & 7;
            int srcb = pb ^ (row & 7);
            gload16((char*)&As[buf][0][0] + (size_t)idx * 16,
                    Ab + (size_t)row * KDIM + kt * 64 + srcb * 8);
        }
#pragma unroll
        for (int rnd = 0; rnd < 4; ++rnd) {
            int idx = rnd * 256 + t;
            int row = idx >> 3, pb = idx & 7;
            int srcb = pb ^ (row & 7);
            gload16((char*)&Bs[buf][0][0] + (size_t)idx * 16,
                    Bb + (size_t)row * KDIM + kt * 64 + srcb * 8);
        }
    };
    auto compute = [&](int buf) {
#pragma unroll
        for (int ks = 0; ks < 2; ++ks) {
            bf16x8 af[4], bfr[4];
#pragma unroll
            for (int mi = 0; mi < 4; ++mi) {
                int r = wr * 64 + mi * 16 + (lane & 15);
                int bi = (ks * 4 + (lane >> 4)) ^ (r & 7);
                af[mi] = *(const bf16x8*)&As[buf][r][bi * 8];
            }
#pragma unroll
            for (int ni = 0; ni < 4; ++ni) {
                int r = wc * 64 + ni * 16 + (lane & 15);
                int bi = (ks * 4 + (lane >> 4)) ^ (r & 7);
                bfr[ni] = *(const bf16x8*)&Bs[buf][r][bi * 8];
            }
#pragma unroll
            for (int mi = 0; mi < 4; ++mi)
#pragma unroll
                for (int ni = 0; ni < 4; ++ni)
                    acc[mi][ni] = __builtin_amdgcn_mfma_f32_16x16x32_bf16(
                        af[mi], bfr[ni], acc[mi][ni], 0, 0, 0);
        }
    };

    stage(0, 0);
    for (int kt = 0; kt < nk; ++kt) {
        const int cur = kt & 1;
        if (kt + 1 < nk) {
            stage(cur ^ 1, kt + 1);
            asm volatile("s_waitcnt vmcnt(8)" ::: "memory");
        } else {
            asm volatile("s_waitcnt vmcnt(0)" ::: "memory");
        }
        __builtin_amdgcn_s_barrier();
        __builtin_amdgcn_sched_barrier(0);
        compute(cur);
        __builtin_amdgcn_s_barrier();
    }

    const int rowb = bm * 128 + wr * 64;
    const int colb = bn * 128 + wc * 64;
#pragma unroll
    for (int mi = 0; mi < 4; ++mi) {
#pragma unroll
        for (int ni = 0; ni < 4; ++ni) {
            int r0 = rowb + mi * 16 + (lane >> 4) * 4;
            int cc = colb + ni * 16 + (lane & 15);
#pragma unroll
            for (int j = 0; j < 4; ++j)
                outp[((size_t)b * C_ + r0 + j) * N_ + cc] = acc[mi][ni][j] + bias[r0 + j];
        }
    }
}

// ---------------- kstats: per-row max & 1/sum(exp) from klog ----------------
__global__ __launch_bounds__(256) void kstats_k(const bf16* __restrict__ klog,
                                                float2* __restrict__ kstat) {
    const int row = blockIdx.x * 4 + (threadIdx.x >> 6);
    const int lane = threadIdx.x & 63;
    const bf16* rp = klog + (size_t)row * N_;
    float v[16];
    float mx = -1e30f;
#pragma unroll
    for (int i = 0; i < 2; ++i) {
        bf16x8 u = *(const bf16x8*)(rp + ((size_t)lane + 64 * i) * 8);
#pragma unroll
        for (int j = 0; j < 8; ++j) {
            v[i * 8 + j] = (float)u[j];
            mx = fmaxf(mx, v[i * 8 + j]);
        }
    }
#pragma unroll
    for (int off = 32; off >= 1; off >>= 1) mx = fmaxf(mx, __shfl_xor(mx, off));
    float s = 0.f;
#pragma unroll
    for (int i = 0; i < 16; ++i) s += __expf(v[i] - mx);
#pragma unroll
    for (int off = 32; off >= 1; off >>= 1) s += __shfl_xor(s, off);
    if (lane == 0) kstat[row] = make_float2(mx, 1.f / s);
}

// ------- attn1: inline softmax(A) ; partial att[d][e] per (b,h,K-half) -------
__global__ __launch_bounds__(256) void attn1_kernel(const bf16* __restrict__ klog,
                                                    const float2* __restrict__ kstat,
                                                    const bf16* __restrict__ vb,
                                                    float* __restrict__ attP) {
    __shared__ float attp[2][64][64];
    const int blk = blockIdx.x;
    const int bh = blk >> 1, half = blk & 1;
    const int t = threadIdx.x, lane = t & 63, wv = t >> 6;
    const bf16* kb = klog + (size_t)bh * D_ * N_;
    const bf16* vv = vb + (size_t)bh * D_ * N_;

    float2 kst[4];
#pragma unroll
    for (int mi = 0; mi < 4; ++mi)
        kst[mi] = kstat[(size_t)bh * D_ + mi * 16 + (lane & 15)];

    f32x4 acc[4][4];
#pragma unroll
    for (int mi = 0; mi < 4; ++mi)
#pragma unroll
        for (int ni = 0; ni < 4; ++ni) acc[mi][ni] = f32x4{0.f, 0.f, 0.f, 0.f};

    const int k0 = half * 512 + wv * 128;  // K split: 2 blocks x 4 waves x 128
#pragma unroll
    for (int kk = 0; kk < 128; kk += 32) {
        bf16x8 af[4], bfr[4];
#pragma unroll
        for (int mi = 0; mi < 4; ++mi) {
            bf16x8 raw = *(const bf16x8*)(kb + (size_t)(mi * 16 + (lane & 15)) * N_ + k0 + kk + (lane >> 4) * 8);
            bf16x8 a;
#pragma unroll
            for (int j = 0; j < 8; ++j)
                a[j] = (bf16)(__expf((float)raw[j] - kst[mi].x) * kst[mi].y);
            af[mi] = a;
        }
#pragma unroll
        for (int ni = 0; ni < 4; ++ni)
            bfr[ni] = *(const bf16x8*)(vv + (size_t)(ni * 16 + (lane & 15)) * N_ + k0 + kk + (lane >> 4) * 8);
#pragma unroll
        for (int mi = 0; mi < 4; ++mi)
#pragma unroll
            for (int ni = 0; ni < 4; ++ni)
                acc[mi][ni] = __builtin_amdgcn_mfma_f32_16x16x32_bf16(
                    af[mi], bfr[ni], acc[mi][ni], 0, 0, 0);
    }
    if (wv < 2) {
#pragma unroll
        for (int mi = 0; mi < 4; ++mi)
#pragma unroll
            for (int ni = 0; ni < 4; ++ni)
#pragma unroll
                for (int j = 0; j < 4; ++j)
                    attp[wv][mi * 16 + (lane >> 4) * 4 + j][ni * 16 + (lane & 15)] = acc[mi][ni][j];
    }
    __syncthreads();
    if (wv >= 2) {
#pragma unroll
        for (int mi = 0; mi < 4; ++mi)
#pragma unroll
            for (int ni = 0; ni < 4; ++ni)
#pragma unroll
                for (int j = 0; j < 4; ++j)
                    attp[wv - 2][mi * 16 + (lane >> 4) * 4 + j][ni * 16 + (lane & 15)] += acc[mi][ni][j];
    }
    __syncthreads();
    float* op = attP + (size_t)blk * 4096;  // [d][e], e contiguous
    for (int i = t; i < 4096; i += 256) {
        int d = i >> 6, e = i & 63;
        op[i] = attp[0][d][e] + attp[1][d][e];
    }
}

// ------- attn2: out2 = attT * qT^T, one n-quarter per block (512 blocks) ------
__global__ __launch_bounds__(256) void attn2_kernel(const float* __restrict__ attP,
                                                    const bf16* __restrict__ qT,
                                                    bf16* __restrict__ o2T) {
    __shared__ __align__(16) bf16 attT[64][64];  // XOR-swizzled cols
    const int blk = blockIdx.x;
    const int bh = blk >> 2, nc = blk & 3;
    const int b = bh >> 3, h = bh & 7;
    const int t = threadIdx.x, lane = t & 63, wv = t >> 6;
    const float* p0 = attP + (size_t)(bh * 2) * 4096;
    const float* p1 = p0 + 4096;
    for (int i = t; i < 4096; i += 256) {
        int d = i >> 6, e = i & 63;
        attT[e][d ^ ((e & 7) << 3)] = (bf16)(p0[i] + p1[i]);
    }
    __syncthreads();

    const bf16* qb = qT + (size_t)bh * N_ * D_;
    const int n0 = nc * 256 + wv * 64;
    f32x4 a2[4][4];
#pragma unroll
    for (int mi = 0; mi < 4; ++mi)
#pragma unroll
        for (int ni = 0; ni < 4; ++ni) a2[mi][ni] = f32x4{0.f, 0.f, 0.f, 0.f};
#pragma unroll
    for (int ks = 0; ks < 2; ++ks) {
        bf16x8 af[4], bfr[4];
#pragma unroll
        for (int mi = 0; mi < 4; ++mi) {
            int r = mi * 16 + (lane & 15);
            int cb = ks * 32 + (lane >> 4) * 8;
            af[mi] = *(const bf16x8*)&attT[r][cb ^ ((r & 7) << 3)];
        }
#pragma unroll
        for (int ni = 0; ni < 4; ++ni)
            bfr[ni] = *(const bf16x8*)(qb + (size_t)(n0 + ni * 16 + (lane & 15)) * D_ + ks * 32 + (lane >> 4) * 8);
#pragma unroll
        for (int mi = 0; mi < 4; ++mi)
#pragma unroll
            for (int ni = 0; ni < 4; ++ni)
                a2[mi][ni] = __builtin_amdgcn_mfma_f32_16x16x32_bf16(
                    af[mi], bfr[ni], a2[mi][ni], 0, 0, 0);
    }
#pragma unroll
    for (int mi = 0; mi < 4; ++mi) {
#pragma unroll
        for (int ni = 0; ni < 4; ++ni) {
            int e0 = mi * 16 + (lane >> 4) * 4;
            int nn = n0 + ni * 16 + (lane & 15);
            bf16x4 pk;
#pragma unroll
            for (int j = 0; j < 4; ++j) pk[j] = (bf16)a2[mi][ni][j];
            *(bf16x4*)(o2T + ((size_t)b * N_ + nn) * C_ + h * D_ + e0) = pk;
        }
    }
}

extern "C" void kernel_launch(void* const* d_in, const int* in_sizes, int n_in,
                              void* d_out, int out_size, void* d_ws, size_t ws_size,
                              hipStream_t stream) {
    const float* x = (const float*)d_in[0];
    const float* gn_scale = (const float*)d_in[1];
    const float* gn_bias = (const float*)d_in[2];
    const float* qkv_w = (const float*)d_in[3];
    const float* proj_w = (const float*)d_in[4];
    const float* proj_b = (const float*)d_in[5];
    float* out = (float*)d_out;

    const size_t elems = (size_t)B_ * C_ * N_;           // 8,388,608
    const size_t plane = (size_t)B_ * HEADS_ * D_ * N_;  // 8,388,608
    char* w = (char*)d_ws;
    bf16* xnT = (bf16*)w;    w += elems * 2;               // 16.8 MB (reused as o2T)
    bf16* qT = (bf16*)w;     w += plane * 2;               // 16.8 MB
    bf16* klog = (bf16*)w;   w += plane * 2;               // 16.8 MB
    bf16* vbuf = (bf16*)w;   w += plane * 2;               // 16.8 MB
    float* attP = (float*)w; w += (size_t)256 * 4096 * 4;  // 4.2 MB
    float2* kstat = (float2*)w; w += (size_t)8192 * 8;     // 64 KB
    bf16* wqkv = (bf16*)w;   w += (size_t)3 * C_ * C_ * 2; // 1.5 MB
    bf16* wproj = (bf16*)w;  w += (size_t)C_ * C_ * 2;     // 0.5 MB
    bf16* o2T = xnT;  // xnT dead after qkv GEMM; alias

    convert_w<<<1024, 256, 0, stream>>>(qkv_w, proj_w, wqkv, wproj);
    gn_kernel<<<512, 256, 0, stream>>>(x, gn_scale, gn_bias, xnT);
    qkv_gemm<<<dim3(8, 12, 16), 256, 0, stream>>>(wqkv, xnT, qT, klog, vbuf);
    kstats_k<<<2048, 256, 0, stream>>>(klog, kstat);
    attn1_kernel<<<256, 256, 0, stream>>>(klog, kstat, vbuf, attP);
    attn2_kernel<<<512, 256, 0, stream>>>(attP, qT, o2T);
    proj_gemm<<<dim3(8, 4, 16), 256, 0, stream>>>(wproj, o2T, out, proj_b);
}